// Round 10
// baseline (211.016 us; speedup 1.0000x reference)
//
#include <hip/hip_runtime.h>
#include <hip/hip_bf16.h>

#define NROWS 131072
#define KIN   784
#define H1N   128
#define H2N   64
#define OUTN  10

// chunked weight layouts: w1c[kb][col][8] with kb = k/8  (k in [0,800))
#define W1C_ELEMS (100 * 128 * 8)   // 102400
#define W2C_ELEMS (16 * 64 * 8)     // 8192
#define W3_ELEMS  (16 * 64)         // 1024

typedef short s16x8 __attribute__((ext_vector_type(8)));
typedef float f32x4 __attribute__((ext_vector_type(4)));

typedef __hip_bfloat16 bf16;

static __device__ __forceinline__ short b2s(float f) {
    bf16 h = __float2bfloat16(f);
    return *reinterpret_cast<short*>(&h);
}

static __device__ __forceinline__ s16x8 cvt8(f32x4 a, f32x4 b) {
    s16x8 r;
    r[0] = b2s(a[0]); r[1] = b2s(a[1]); r[2] = b2s(a[2]); r[3] = b2s(a[3]);
    r[4] = b2s(b[0]); r[5] = b2s(b[1]); r[6] = b2s(b[2]); r[7] = b2s(b[3]);
    return r;
}

// async global -> LDS: 16B/lane, per-lane global addr, wave-uniform LDS base
static __device__ __forceinline__ void gl2lds16(const void* g, char* l) {
    __builtin_amdgcn_global_load_lds(
        (const __attribute__((address_space(1))) void*)g,
        (__attribute__((address_space(3))) void*)l, 16, 0, 0);
}
// NT (stream) variant for the read-once x stream: aux bit1 = NT on gfx94x/95x
static __device__ __forceinline__ void gl2lds16_nt(const void* g, char* l) {
    __builtin_amdgcn_global_load_lds(
        (const __attribute__((address_space(1))) void*)g,
        (__attribute__((address_space(3))) void*)l, 16, 0, 2);
}

#define WAITV(N) do { asm volatile("s_waitcnt vmcnt(" #N ")" ::: "memory"); \
                      __builtin_amdgcn_sched_barrier(0); } while (0)
#define WAITL()  do { asm volatile("s_waitcnt lgkmcnt(0)" ::: "memory"); \
                      __builtin_amdgcn_sched_barrier(0); } while (0)
#define BAR()    __builtin_amdgcn_s_barrier()

// ---------------- dequant: int4(int32) * f32 scale -> bf16 (chunked layouts) --
__global__ __launch_bounds__(256) void dequant_kernel(
    const int* __restrict__ w1q, const float* __restrict__ s1,
    const int* __restrict__ w2q, const float* __restrict__ s2,
    const int* __restrict__ w3q, const float* __restrict__ s3,
    bf16* __restrict__ w1c, bf16* __restrict__ w2c, bf16* __restrict__ w3d)
{
    const int total = W1C_ELEMS + W2C_ELEMS + W3_ELEMS;
    for (int i = blockIdx.x * blockDim.x + threadIdx.x; i < total;
         i += gridDim.x * blockDim.x) {
        if (i < W1C_ELEMS) {
            int kb = i >> 10, rem = i & 1023;
            int col = rem >> 3, j = rem & 7;
            int k = kb * 8 + j;
            float v = 0.0f;
            if (k < KIN) v = (float)w1q[col * KIN + k] * s1[col];
            w1c[i] = __float2bfloat16(v);
        } else if (i < W1C_ELEMS + W2C_ELEMS) {
            int t = i - W1C_ELEMS;
            int kb = t >> 9, rem = t & 511;
            int col = rem >> 3, j = rem & 7;
            int k = kb * 8 + j;
            w2c[t] = __float2bfloat16((float)w2q[col * H1N + k] * s2[col]);
        } else {
            int t = i - W1C_ELEMS - W2C_ELEMS;
            int r = t >> 6, c = t & 63;
            float v = 0.0f;
            if (r < OUTN) v = (float)w3q[r * H2N + c] * s3[r];
            w3d[t] = __float2bfloat16(v);
        }
    }
}

// ---------------- fused MLP ------------------------------------------------
// 512 threads (8 waves), BM=128 rows/block, wave owns 16 rows (same per-wave
// shape as r8). A(x, NT-hinted) + B(W1) staged via global_load_lds into a
// 2-slot ring: A slots 2x16KB (wave-private 2KB lanes), B slots 2x8KB
// (block-shared). Uniform 3-gl_lds/window per wave -> WAITV(3) keeps ~2
// windows airborne. 2 raw s_barriers/window. LDS 48KB -> 3 blocks/CU;
// launch_bounds(512,6) targets VGPR<=85 -> 24 waves/CU. B re-reads halved
// vs r8 (1024 blocks x 200KB).
__global__ __launch_bounds__(512, 6) void mlp_kernel(
    const float* __restrict__ x,
    const bf16*  __restrict__ w1c,
    const bf16*  __restrict__ w2c,
    const bf16*  __restrict__ w3d,
    const float* __restrict__ b1,
    const float* __restrict__ b2,
    const float* __restrict__ b3,
    float* __restrict__ out)
{
    __shared__ __align__(16) char lds[49152];
    // [0,32K): A slots 2x16KB (slot s: wave wv at +wv*2048 = 16 rows x 128B,
    //          seg-swizzled). [32K,48K): B slots 2x8KB (verbatim w1c window).
    // post-loop: per-wave arenas at lds + wv*4224 (ring dead, after final BAR).

    const int tid  = threadIdx.x;
    const int lane = tid & 63;
    const int wv   = tid >> 6;      // 0..7
    const int r16  = lane & 15;
    const int kg   = lane >> 4;     // 0..3
    const int kgo  = kg * 8;

    const int i3 = lane >> 3;       // staging row-in-group 0..7
    const int i7 = lane & 7;        // staging LDS 16B-slot 0..7
    const int sw = i7 ^ i3;         // swizzled global seg index
    const int adj = (sw >= 4) ? 16 : 0;   // tail-window in-row redirect

    const long long rowW = (long long)blockIdx.x * 128 + wv * 16;
    const float* gA  = x + (rowW + i3) * (long long)KIN + sw * 4;
    const bf16*  gBw = w1c + (size_t)wv * 512 + (size_t)lane * 8;

    // consume offsets: row r16 of wave's 2KB lane; aoff1 = aoff0 ^ 16
    const int aoff0 = wv * 2048 + r16 * 128 + (((2 * kg) ^ (r16 & 7)) * 16);
    const int boffc = 32768 + kg * 2048 + r16 * 16;

    // prologue: stage windows 0,1
#pragma unroll
    for (int w = 0; w < 2; ++w) {
        char* ad = lds + w * 16384 + wv * 2048;
        const float* g = gA + w * 32;
        gl2lds16_nt(g, ad);
        gl2lds16_nt(g + 8 * KIN, ad + 1024);
        gl2lds16(gBw + (size_t)w * 4096, lds + 32768 + w * 8192 + wv * 1024);
    }

    f32x4 acc1[8];
#pragma unroll
    for (int j = 0; j < 8; ++j) acc1[j] = (f32x4){0.f, 0.f, 0.f, 0.f};

#pragma unroll 1
    for (int t = 0; t < 24; ++t) {
        WAITV(3);                 // this wave's window-t ops retired
        BAR();                    // all waves' shares landed
        const char* sa = lds + (t & 1) * 16384;
        f32x4 q0 = *(const f32x4*)(sa + aoff0);
        f32x4 q1 = *(const f32x4*)(sa + (aoff0 ^ 16));
        const char* sb = lds + (t & 1) * 8192 + boffc;
        s16x8 bw[8];
#pragma unroll
        for (int nj = 0; nj < 8; ++nj) bw[nj] = *(const s16x8*)(sb + nj * 256);
        WAITL();                  // reads in registers
        BAR();                    // all waves done reading slot t&1
        if (t < 22) {             // stage window t+2 into the freed slot
            char* ad = lds + (t & 1) * 16384 + wv * 2048;
            const float* g = gA + (t + 2) * 32;
            gl2lds16_nt(g, ad);
            gl2lds16_nt(g + 8 * KIN, ad + 1024);
            gl2lds16(gBw + (size_t)(t + 2) * 4096,
                     lds + 32768 + (t & 1) * 8192 + wv * 1024);
        } else if (t == 22) {     // window 24: segs>=4 redirected in-row
            char* ad = lds + (t & 1) * 16384 + wv * 2048;
            const float* g = gA + 768 - adj;
            gl2lds16_nt(g, ad);
            gl2lds16_nt(g + 8 * KIN, ad + 1024);
            gl2lds16(gBw + (size_t)24 * 4096,
                     lds + 32768 + (t & 1) * 8192 + wv * 1024);
        }
        s16x8 a = cvt8(q0, q1);
#pragma unroll
        for (int nj = 0; nj < 8; ++nj)
            acc1[nj] = __builtin_amdgcn_mfma_f32_16x16x32_bf16(a, bw[nj], acc1[nj], 0, 0, 0);
    }
    {   // peeled window 24 (k 768..799; weights zero for k>=784)
        WAITV(0);
        BAR();
        const char* sa = lds;     // slot 0
        f32x4 q0 = *(const f32x4*)(sa + aoff0);
        f32x4 q1 = *(const f32x4*)(sa + (aoff0 ^ 16));
        const char* sb = lds + boffc;
        s16x8 bw[8];
#pragma unroll
        for (int nj = 0; nj < 8; ++nj) bw[nj] = *(const s16x8*)(sb + nj * 256);
        WAITL();
        BAR();                    // ring fully dead -> arenas may overlay
        s16x8 a = cvt8(q0, q1);
#pragma unroll
        for (int nj = 0; nj < 8; ++nj)
            acc1[nj] = __builtin_amdgcn_mfma_f32_16x16x32_bf16(a, bw[nj], acc1[nj], 0, 0, 0);
    }

    // ---- per-wave arena (4224B): h1[16][132] -> h2[16][68] -> out stage ----
    char* ar = lds + wv * 4224;
    short (*h1w)[132] = (short(*)[132])ar;
#pragma unroll
    for (int nj = 0; nj < 8; ++nj) {
        const int col = nj * 16 + r16;
        const float bb = b1[col];
#pragma unroll
        for (int r = 0; r < 4; ++r)
            h1w[kg * 4 + r][col] = b2s(fmaxf(acc1[nj][r] + bb, 0.0f));
    }

    // ---- layer 2: [16 x 128] @ [128 x 64] per wave ----
    f32x4 acc2[4];
#pragma unroll
    for (int j = 0; j < 4; ++j) acc2[j] = (f32x4){0.f, 0.f, 0.f, 0.f};

#pragma unroll
    for (int it = 0; it < 4; ++it) {
        const int kk = it * 32 + kgo;
        s16x8 a = *(const s16x8*)&h1w[r16][kk];
        const bf16* bp2 = w2c + (size_t)(it * 4 + kg) * 512 + (size_t)r16 * 8;
#pragma unroll
        for (int nj = 0; nj < 4; ++nj) {
            s16x8 b = *(const s16x8*)(bp2 + nj * 128);
            acc2[nj] = __builtin_amdgcn_mfma_f32_16x16x32_bf16(a, b, acc2[nj], 0, 0, 0);
        }
    }

    short (*h2w)[68] = (short(*)[68])ar;   // same-wave overlay
#pragma unroll
    for (int nj = 0; nj < 4; ++nj) {
        const int col = nj * 16 + r16;
        const float bb = b2[col];
#pragma unroll
        for (int r = 0; r < 4; ++r)
            h2w[kg * 4 + r][col] = b2s(fmaxf(acc2[nj][r] + bb, 0.0f));
    }

    // ---- layer 3: [16 x 64] @ [64 x 16] (rows 10..15 of W3 are zero) ----
    f32x4 acc3 = (f32x4){0.f, 0.f, 0.f, 0.f};
#pragma unroll
    for (int it = 0; it < 2; ++it) {
        const int kk = it * 32 + kgo;
        s16x8 a = *(const s16x8*)&h2w[r16][kk];
        s16x8 b = *(const s16x8*)(w3d + r16 * H2N + kk);
        acc3 = __builtin_amdgcn_mfma_f32_16x16x32_bf16(a, b, acc3, 0, 0, 0);
    }

    float* ob = (float*)ar;   // 640B out stage, overlay after h2 reads
    const float bb3 = (r16 < OUTN) ? b3[r16] : 0.0f;
#pragma unroll
    for (int r = 0; r < 4; ++r) {
        const int row = kg * 4 + r;
        if (r16 < OUTN) ob[row * OUTN + r16] = acc3[r] + bb3;
    }
    const long long obase = rowW * OUTN;
    for (int i = lane; i < 16 * OUTN; i += 64) out[obase + i] = ob[i];
}

extern "C" void kernel_launch(void* const* d_in, const int* in_sizes, int n_in,
                              void* d_out, int out_size, void* d_ws, size_t ws_size,
                              hipStream_t stream) {
    const float* x   = (const float*)d_in[0];
    const int*   w1q = (const int*)d_in[1];
    const float* s1  = (const float*)d_in[2];
    const float* b1  = (const float*)d_in[3];
    const int*   w2q = (const int*)d_in[4];
    const float* s2  = (const float*)d_in[5];
    const float* b2  = (const float*)d_in[6];
    const int*   w3q = (const int*)d_in[7];
    const float* s3  = (const float*)d_in[8];
    const float* b3  = (const float*)d_in[9];
    float* out = (float*)d_out;

    bf16* w1c = (bf16*)d_ws;              // [100][128][8]
    bf16* w2c = w1c + W1C_ELEMS;          // [16][64][8]
    bf16* w3d = w2c + W2C_ELEMS;          // [16][64]

    dequant_kernel<<<128, 256, 0, stream>>>(w1q, s1, w2q, s2, w3q, s3, w1c, w2c, w3d);
    mlp_kernel<<<NROWS / 128, 512, 0, stream>>>(x, w1c, w2c, w3d, b1, b2, b3, out);
}

// Round 11
// 117.651 us; speedup vs baseline: 1.7936x; 1.7936x over previous
//
#include <hip/hip_runtime.h>
#include <hip/hip_bf16.h>

#define NROWS 131072
#define KIN   784
#define H1N   128
#define H2N   64
#define OUTN  10

// packed W1: w1p[kb][kg][col_s] dword; kb=0..24 (K=32 windows), kg=0..3,
// col_s = (col + 8*kg) & 127; nibble j = int4 of w1q[col][kb*32+kg*8+j]
// (zero for k >= 784). 25*4*128 dwords = 50 KB total.
#define W1P_DWORDS (25 * 4 * 128)   // 12800
#define W2C_ELEMS  (16 * 64 * 8)    // 8192  (bf16, k-chunked as before)
#define W3_ELEMS   (16 * 64)        // 1024  (bf16)

typedef short s16x8 __attribute__((ext_vector_type(8)));
typedef float f32x4 __attribute__((ext_vector_type(4)));

typedef __hip_bfloat16 bf16;

static __device__ __forceinline__ short b2s(float f) {
    bf16 h = __float2bfloat16(f);
    return *reinterpret_cast<short*>(&h);
}

static __device__ __forceinline__ s16x8 cvt8(f32x4 a, f32x4 b) {
    s16x8 r;
    r[0] = b2s(a[0]); r[1] = b2s(a[1]); r[2] = b2s(a[2]); r[3] = b2s(a[3]);
    r[4] = b2s(b[0]); r[5] = b2s(b[1]); r[6] = b2s(b[2]); r[7] = b2s(b[3]);
    return r;
}

// unpack 8 int4 nibbles -> bf16x8 fragment (values -8..7, exact in bf16)
static __device__ __forceinline__ s16x8 unpack8(unsigned d) {
    s16x8 r;
#pragma unroll
    for (int j = 0; j < 8; ++j) {
        int v = ((int)(d << (28 - 4 * j))) >> 28;   // v_bfe_i32
        r[j] = b2s((float)v);
    }
    return r;
}

// async global -> LDS: per-lane global addr, wave-uniform LDS base
static __device__ __forceinline__ void gl2lds16(const void* g, char* l) {
    __builtin_amdgcn_global_load_lds(
        (const __attribute__((address_space(1))) void*)g,
        (__attribute__((address_space(3))) void*)l, 16, 0, 0);
}
static __device__ __forceinline__ void gl2lds4(const void* g, char* l) {
    __builtin_amdgcn_global_load_lds(
        (const __attribute__((address_space(1))) void*)g,
        (__attribute__((address_space(3))) void*)l, 4, 0, 0);
}

#define WAITV(N) do { asm volatile("s_waitcnt vmcnt(" #N ")" ::: "memory"); \
                      __builtin_amdgcn_sched_barrier(0); } while (0)
#define WAITL()  do { asm volatile("s_waitcnt lgkmcnt(0)" ::: "memory"); \
                      __builtin_amdgcn_sched_barrier(0); } while (0)
#define BAR()    __builtin_amdgcn_s_barrier()

// ---------------- prep: pack W1 int4 nibbles; dequant W2/W3 to bf16 ----------
__global__ __launch_bounds__(256) void dequant_kernel(
    const int* __restrict__ w1q, const float* __restrict__ s1,
    const int* __restrict__ w2q, const float* __restrict__ s2,
    const int* __restrict__ w3q, const float* __restrict__ s3,
    unsigned* __restrict__ w1p, bf16* __restrict__ w2c, bf16* __restrict__ w3d)
{
    const int total = W1P_DWORDS + W2C_ELEMS + W3_ELEMS;
    for (int i = blockIdx.x * blockDim.x + threadIdx.x; i < total;
         i += gridDim.x * blockDim.x) {
        if (i < W1P_DWORDS) {
            int kb = i >> 9, rem = i & 511;
            int kg = rem >> 7, col_s = rem & 127;
            int col = (col_s - 8 * kg) & 127;
            unsigned d = 0;
#pragma unroll
            for (int j = 0; j < 8; ++j) {
                int k = kb * 32 + kg * 8 + j;
                unsigned q = 0;
                if (k < KIN) q = (unsigned)w1q[col * KIN + k] & 0xFu;
                d |= q << (4 * j);
            }
            w1p[i] = d;
        } else if (i < W1P_DWORDS + W2C_ELEMS) {
            int t = i - W1P_DWORDS;
            int kb = t >> 9, rem = t & 511;
            int col = rem >> 3, j = rem & 7;
            int k = kb * 8 + j;
            w2c[t] = __float2bfloat16((float)w2q[col * H1N + k] * s2[col]);
        } else {
            int t = i - W1P_DWORDS - W2C_ELEMS;
            int r = t >> 6, c = t & 63;
            float v = 0.0f;
            if (r < OUTN) v = (float)w3q[r * H2N + c] * s3[r];
            w3d[t] = __float2bfloat16(v);
        }
    }
}

// ---------------- fused MLP ------------------------------------------------
// r8 structure (256 thr / 4 waves / BM=64 / wave owns 16 rows / 2-slot ring /
// WAITV(4) / 2 raw barriers per window), with W1 staged as PACKED INT4
// (2KB/window vs 8KB bf16): B traffic 410->102 MB, LDS 32->20KB -> 6
// blocks/CU = 24 waves. Scale folded out of the K-loop: acc uses exact int
// weights, s_col applied once in the epilogue (accuracy improves).
__global__ __launch_bounds__(256, 6) void mlp_kernel(
    const float* __restrict__ x,
    const unsigned* __restrict__ w1p,
    const bf16*  __restrict__ w2c,
    const bf16*  __restrict__ w3d,
    const float* __restrict__ s1,
    const float* __restrict__ b1,
    const float* __restrict__ b2,
    const float* __restrict__ b3,
    float* __restrict__ out)
{
    __shared__ __align__(16) char lds[20480];
    // A slots: [0,8K),[8K,16K)  (slot: wave wv at +wv*2048 = 16 rows x 128B,
    //          seg-swizzled).  B slots: [16K,18K),[18K,20K) (packed window).
    // post-loop per-wave arenas at lds + wv*4224 (ring dead after final BAR).

    const int tid  = threadIdx.x;
    const int lane = tid & 63;
    const int wv   = tid >> 6;
    const int r16  = lane & 15;
    const int kg   = lane >> 4;     // 0..3
    const int kgo  = kg * 8;

    const int i3 = lane >> 3;       // staging row-in-group 0..7
    const int i7 = lane & 7;        // staging LDS 16B-slot 0..7
    const int sw = i7 ^ i3;         // swizzled global seg index
    const int adj = (sw >= 4) ? 16 : 0;   // tail-window in-row redirect

    const long long rowW = (long long)blockIdx.x * 64 + wv * 16;
    const float* gA = x + (rowW + i3) * (long long)KIN + sw * 4;
    const unsigned* gB = w1p + wv * 128 + lane;   // + win*512 (+64 for 2nd op)

    // consume offsets
    const int aoff0 = wv * 2048 + r16 * 128 + (((2 * kg) ^ (r16 & 7)) * 16);
    // B frag nj dword: 16K + slot*2K + kg*512 + ((nj*16+r16+8*kg)&127)*4

    // prologue: stage windows 0,1 (A,A,B,B = 4 ops per wave per window)
#pragma unroll
    for (int w = 0; w < 2; ++w) {
        char* ad = lds + w * 8192 + wv * 2048;
        gl2lds16(gA + w * 32, ad);
        gl2lds16(gA + w * 32 + 8 * KIN, ad + 1024);
        char* bd = lds + 16384 + w * 2048 + wv * 512;
        const unsigned* gb = gB + w * 512;
        gl2lds4(gb, bd);
        gl2lds4(gb + 64, bd + 256);
    }

    f32x4 acc1[8];
#pragma unroll
    for (int j = 0; j < 8; ++j) acc1[j] = (f32x4){0.f, 0.f, 0.f, 0.f};

#pragma unroll 1
    for (int t = 0; t < 24; ++t) {
        WAITV(4);                 // this wave's window-t ops retired
        BAR();                    // all waves' shares landed
        const char* sa = lds + (t & 1) * 8192;
        f32x4 q0 = *(const f32x4*)(sa + aoff0);
        f32x4 q1 = *(const f32x4*)(sa + (aoff0 ^ 16));
        const char* sbB = lds + 16384 + (t & 1) * 2048 + kg * 512;
        unsigned bd[8];
#pragma unroll
        for (int nj = 0; nj < 8; ++nj)
            bd[nj] = *(const unsigned*)(sbB + (((nj * 16 + r16 + 8 * kg) & 127) << 2));
        WAITL();                  // reads in registers
        BAR();                    // all waves done reading slot t&1
        if (t < 22) {             // stage window t+2 into the freed slot
            char* ad = lds + (t & 1) * 8192 + wv * 2048;
            const float* g = gA + (t + 2) * 32;
            gl2lds16(g, ad);
            gl2lds16(g + 8 * KIN, ad + 1024);
            char* bdst = lds + 16384 + (t & 1) * 2048 + wv * 512;
            const unsigned* gb = gB + (t + 2) * 512;
            gl2lds4(gb, bdst);
            gl2lds4(gb + 64, bdst + 256);
        } else if (t == 22) {     // window 24: A segs>=4 redirected in-row
            char* ad = lds + (t & 1) * 8192 + wv * 2048;
            const float* g = gA + 768 - adj;
            gl2lds16(g, ad);
            gl2lds16(g + 8 * KIN, ad + 1024);
            char* bdst = lds + 16384 + (t & 1) * 2048 + wv * 512;
            const unsigned* gb = gB + 24 * 512;
            gl2lds4(gb, bdst);
            gl2lds4(gb + 64, bdst + 256);
        }
        s16x8 a = cvt8(q0, q1);
#pragma unroll
        for (int nj = 0; nj < 8; ++nj) {
            s16x8 bf = unpack8(bd[nj]);
            acc1[nj] = __builtin_amdgcn_mfma_f32_16x16x32_bf16(a, bf, acc1[nj], 0, 0, 0);
        }
    }
    {   // peeled window 24 (k 768..799; packed weights zero for k>=784)
        WAITV(0);
        BAR();
        const char* sa = lds;     // slot 0
        f32x4 q0 = *(const f32x4*)(sa + aoff0);
        f32x4 q1 = *(const f32x4*)(sa + (aoff0 ^ 16));
        const char* sbB = lds + 16384 + kg * 512;
        unsigned bd[8];
#pragma unroll
        for (int nj = 0; nj < 8; ++nj)
            bd[nj] = *(const unsigned*)(sbB + (((nj * 16 + r16 + 8 * kg) & 127) << 2));
        WAITL();
        BAR();                    // ring fully dead -> arenas may overlay
        s16x8 a = cvt8(q0, q1);
#pragma unroll
        for (int nj = 0; nj < 8; ++nj) {
            s16x8 bf = unpack8(bd[nj]);
            acc1[nj] = __builtin_amdgcn_mfma_f32_16x16x32_bf16(a, bf, acc1[nj], 0, 0, 0);
        }
    }

    // ---- per-wave arena (4224B): h1[16][132] -> h2[16][68] -> out stage ----
    // layer-1 epilogue: apply folded scale, bias, relu
    char* ar = lds + wv * 4224;
    short (*h1w)[132] = (short(*)[132])ar;
#pragma unroll
    for (int nj = 0; nj < 8; ++nj) {
        const int col = nj * 16 + r16;
        const float sc = s1[col];
        const float bb = b1[col];
#pragma unroll
        for (int r = 0; r < 4; ++r)
            h1w[kg * 4 + r][col] = b2s(fmaxf(acc1[nj][r] * sc + bb, 0.0f));
    }

    // ---- layer 2: [16 x 128] @ [128 x 64] per wave ----
    f32x4 acc2[4];
#pragma unroll
    for (int j = 0; j < 4; ++j) acc2[j] = (f32x4){0.f, 0.f, 0.f, 0.f};

#pragma unroll
    for (int it = 0; it < 4; ++it) {
        const int kk = it * 32 + kgo;
        s16x8 a = *(const s16x8*)&h1w[r16][kk];
        const bf16* bp2 = w2c + (size_t)(it * 4 + kg) * 512 + (size_t)r16 * 8;
#pragma unroll
        for (int nj = 0; nj < 4; ++nj) {
            s16x8 b = *(const s16x8*)(bp2 + nj * 128);
            acc2[nj] = __builtin_amdgcn_mfma_f32_16x16x32_bf16(a, b, acc2[nj], 0, 0, 0);
        }
    }

    short (*h2w)[68] = (short(*)[68])ar;   // same-wave overlay
#pragma unroll
    for (int nj = 0; nj < 4; ++nj) {
        const int col = nj * 16 + r16;
        const float bb = b2[col];
#pragma unroll
        for (int r = 0; r < 4; ++r)
            h2w[kg * 4 + r][col] = b2s(fmaxf(acc2[nj][r] + bb, 0.0f));
    }

    // ---- layer 3: [16 x 64] @ [64 x 16] (rows 10..15 of W3 are zero) ----
    f32x4 acc3 = (f32x4){0.f, 0.f, 0.f, 0.f};
#pragma unroll
    for (int it = 0; it < 2; ++it) {
        const int kk = it * 32 + kgo;
        s16x8 a = *(const s16x8*)&h2w[r16][kk];
        s16x8 b = *(const s16x8*)(w3d + r16 * H2N + kk);
        acc3 = __builtin_amdgcn_mfma_f32_16x16x32_bf16(a, b, acc3, 0, 0, 0);
    }

    float* ob = (float*)ar;   // 640B out stage, overlay after h2 reads
    const float bb3 = (r16 < OUTN) ? b3[r16] : 0.0f;
#pragma unroll
    for (int r = 0; r < 4; ++r) {
        const int row = kg * 4 + r;
        if (r16 < OUTN) ob[row * OUTN + r16] = acc3[r] + bb3;
    }
    const long long obase = rowW * OUTN;
    for (int i = lane; i < 16 * OUTN; i += 64) out[obase + i] = ob[i];
}

extern "C" void kernel_launch(void* const* d_in, const int* in_sizes, int n_in,
                              void* d_out, int out_size, void* d_ws, size_t ws_size,
                              hipStream_t stream) {
    const float* x   = (const float*)d_in[0];
    const int*   w1q = (const int*)d_in[1];
    const float* s1  = (const float*)d_in[2];
    const float* b1  = (const float*)d_in[3];
    const int*   w2q = (const int*)d_in[4];
    const float* s2  = (const float*)d_in[5];
    const float* b2  = (const float*)d_in[6];
    const int*   w3q = (const int*)d_in[7];
    const float* s3  = (const float*)d_in[8];
    const float* b3  = (const float*)d_in[9];
    float* out = (float*)d_out;

    unsigned* w1p = (unsigned*)d_ws;                 // 12800 dwords
    bf16* w2c = (bf16*)(w1p + W1P_DWORDS);           // [16][64][8]
    bf16* w3d = w2c + W2C_ELEMS;                     // [16][64]

    dequant_kernel<<<128, 256, 0, stream>>>(w1q, s1, w2q, s2, w3q, s3, w1p, w2c, w3d);
    mlp_kernel<<<NROWS / 64, 256, 0, stream>>>(x, w1p, w2c, w3d, s1, b1, b2, b3, out);
}